// Round 2
// baseline (6214.356 us; speedup 1.0000x reference)
//
#include <hip/hip_runtime.h>
#include <stdint.h>

typedef unsigned int u32;
typedef unsigned long long u64;

#define NN 32768
#define NE 262144
#define NC 128

// output element offsets (ALL FLOAT32)
#define O0 0u               // new_x [NN*128]
#define O1 4194304u         // cluster [NN]
#define O2 4227072u         // new_batch [NN]
#define O3 4259840u         // new_edge_score [NN]
#define O4 4292608u         // num_clusters [1]
#define O5 4292609u         // new_ei [2*NE]
#define O6 4816897u         // edge_valid [NE]
#define O7 5079041u         // e [NE]

#define HCAP (1u<<20)
#define SB 256   // sort blocks
#define SC 1024  // items per sort block

// ---------------- prep: u = W_t @ W_s (f64), c0 = b_t@W_s + b_s; zero counters ----
__global__ void ep_prep(const float* Wt, const float* Ws, const float* bt, const float* bs,
                        double* u, double* c0, u32* counters) {
    int i = threadIdx.x;
    double s = 0.0;
    for (int j = 0; j < NC; j++) s += (double)Wt[i*NC+j] * (double)Ws[j];
    u[i] = s;
    if (i == 0) {
        double c = 0.0;
        for (int j = 0; j < NC; j++) c += (double)bt[j] * (double)Ws[j];
        *c0 = c + (double)bs[0];
    }
    if (i < 64) counters[i] = 0u;
}

// ---------------- per-call state init ----------------
__global__ void ep_init(u32* bestRank, u32* avail, unsigned char* matched, int* cl) {
    int i = blockIdx.x*blockDim.x + threadIdx.x;
    if (i < NE) matched[i] = 0;
    if (i < NN) { bestRank[i] = 0xFFFFFFFFu; cl[i] = -1; }
    if (i < NN/32) avail[i] = 0xFFFFFFFFu;
}

// ---------------- scores: one wave per edge, f64 dot ----------------
__global__ void ep_scores(const float* x, const int* src, const int* dst, const float* rnd,
                          const double* u, const double* c0,
                          u64* keyA, u32* payA, unsigned char* acc, float* out) {
    int gid = blockIdx.x*blockDim.x + threadIdx.x;
    int wid = gid >> 6;
    int lane = threadIdx.x & 63;
    if (wid >= NE) return;
    int s = src[wid], d = dst[wid];
    double m0 = (double)x[s*NC+lane]    + (double)x[d*NC+lane];
    double m1 = (double)x[s*NC+lane+64] + (double)x[d*NC+lane+64];
    double t = m0*u[lane] + m1*u[lane+64];
    for (int off = 32; off; off >>= 1) t += __shfl_down(t, off, 64);
    if (lane == 0) {
        double z = t + *c0;
        double sc = 1.0/(1.0 + exp(-z));
        u64 b = (u64)__double_as_longlong(z);
        u64 ord = (b & 0x8000000000000000ull) ? ~b : (b | 0x8000000000000000ull); // ascending z
        keyA[wid] = ~ord;   // ascending key == descending z
        payA[wid] = (u32)wid;
        acc[wid] = ((double)rnd[wid] <= sc) ? 1 : 0;
        out[O7 + wid] = (float)sc;
    }
}

// ---------------- radix sort (LSD, 8x8-bit, stable) ----------------
__global__ void ep_hist(const u64* key, u32* histG, int shift) {
    __shared__ u32 h[256];
    int t = threadIdx.x; // 64 threads
    for (int i = t; i < 256; i += 64) h[i] = 0;
    __syncthreads();
    int base = blockIdx.x*SC + t*16;
    for (int j = 0; j < 16; j++) {
        u32 dgt = (u32)(key[base+j] >> shift) & 255u;
        atomicAdd(&h[dgt], 1u);
    }
    __syncthreads();
    for (int i = t; i < 256; i += 64) histG[i*SB + blockIdx.x] = h[i];
}

__global__ void ep_hscan(u32* histG) { // exclusive scan of 65536 u32, 1024 threads
    __shared__ u32 w[16];
    int t = threadIdx.x;
    int base = t*64;
    u32 s = 0;
    for (int j = 0; j < 64; j++) s += histG[base+j];
    u32 x = s;
    for (int off = 1; off < 64; off <<= 1) { u32 y = __shfl_up(x, off, 64); if ((t&63) >= off) x += y; }
    if ((t&63) == 63) w[t>>6] = x;
    __syncthreads();
    if (t < 16) {
        u32 ww = w[t];
        for (int off = 1; off < 16; off <<= 1) { u32 y = __shfl_up(ww, off, 16); if (t >= off) ww += y; }
        w[t] = ww;
    }
    __syncthreads();
    u32 excl = ((t>>6) ? w[(t>>6)-1] : 0u) + x - s;
    u32 run = excl;
    for (int j = 0; j < 64; j++) { u32 tmp = histG[base+j]; histG[base+j] = run; run += tmp; }
}

__global__ void ep_scatter(const u64* keyIn, const u32* payIn, u64* keyOut, u32* payOut,
                           const u32* histG, int shift) {
    __shared__ unsigned short m[256][64]; // 32 KiB
    int t = threadIdx.x; // 64 threads
    for (int i = t; i < 256*64/2; i += 64) ((u32*)m)[i] = 0u;
    __syncthreads();
    int base = blockIdx.x*SC + t*16;
    u64 kreg[16]; u32 dg[16];
    #pragma unroll
    for (int j = 0; j < 16; j++) {
        kreg[j] = keyIn[base+j];
        dg[j] = (u32)(kreg[j] >> shift) & 255u;
        m[dg[j]][t]++;
    }
    __syncthreads();
    // digit-local exclusive scans over threads
    for (int k = 0; k < 4; k++) {
        int d = t*4 + k;
        u32 run = 0;
        for (int tt = 0; tt < 64; tt++) { u32 tmp = m[d][tt]; m[d][tt] = (unsigned short)run; run += tmp; }
    }
    __syncthreads();
    #pragma unroll
    for (int j = 0; j < 16; j++) {
        u32 d = dg[j];
        u32 pos = histG[d*SB + blockIdx.x] + m[d][t];
        m[d][t]++;
        keyOut[pos] = kreg[j];
        payOut[pos] = payIn[base+j];
    }
}

// ---------------- frontier build + matching rounds ----------------
__device__ __forceinline__ bool ep_bit(const u32* a, u32 v) { return (a[v>>5] >> (v&31)) & 1u; }

__global__ void ep_build(const u32* pay, const unsigned char* acc, const int* src, const int* dst,
                         u64* front, u32* counters) {
    int r = blockIdx.x*blockDim.x + threadIdx.x;
    if (r >= NE) return;
    u32 o = pay[r];
    if (!acc[o]) return;
    u32 s = (u32)src[o], d = (u32)dst[o];
    u32 p = atomicAdd(&counters[0], 1u);
    front[p] = ((u64)(u32)r << 30) | ((u64)s << 15) | (u64)d;
}

__global__ void ep_roundA(const u64* front, const u32* counters, u32* bestRank, const u32* avail) {
    u32 n = counters[0];
    u32 i = blockIdx.x*blockDim.x + threadIdx.x;
    if (i >= n) return;
    u64 v = front[i];
    u32 r = (u32)(v>>30), s = (u32)((v>>15)&0x7FFF), d = (u32)(v&0x7FFF);
    if (ep_bit(avail, s) && ep_bit(avail, d)) { atomicMin(&bestRank[s], r); atomicMin(&bestRank[d], r); }
}

__global__ void ep_roundB(const u64* front, u32* counters, const u32* bestRank, u32* avail,
                          unsigned char* matched, u64* front2) {
    u32 n = counters[0];
    u32 i = blockIdx.x*blockDim.x + threadIdx.x;
    if (i >= n) return;
    u64 v = front[i];
    u32 r = (u32)(v>>30), s = (u32)((v>>15)&0x7FFF), d = (u32)(v&0x7FFF);
    if (!ep_bit(avail, s) || !ep_bit(avail, d)) return; // dead
    if (bestRank[s] == r && bestRank[d] == r) {
        matched[r] = 1;
        atomicAnd(&avail[s>>5], ~(1u<<(s&31)));
        atomicAnd(&avail[d>>5], ~(1u<<(d&31)));
    } else {
        u32 p = atomicAdd(&counters[1], 1u);
        front2[p] = v;
    }
}

__global__ void ep_roundC(u32* bestRank) {
    int i = blockIdx.x*blockDim.x + threadIdx.x;
    if (i < NN) bestRank[i] = 0xFFFFFFFFu;
}

__global__ void __launch_bounds__(1024) ep_finish(u64* fa, u64* fb, u32* counters,
                                                  u32* bestRank, u32* avail, unsigned char* matched) {
    __shared__ u32 scnt;
    int t = threadIdx.x;
    u64* cur = fa; u64* nxt = fb;
    u32 cnt = counters[1];
    for (int round = 0; round < 40000; round++) {
        if (cnt == 0) break;
        // phase A (atomic reads: avoid stale L1 across rounds)
        for (u32 i = t; i < cnt; i += 1024) {
            u64 v = cur[i];
            u32 r = (u32)(v>>30), s = (u32)((v>>15)&0x7FFF), d = (u32)(v&0x7FFF);
            u32 as = atomicOr(&avail[s>>5], 0u), ad = atomicOr(&avail[d>>5], 0u);
            if (((as>>(s&31))&1u) && ((ad>>(d&31))&1u)) { atomicMin(&bestRank[s], r); atomicMin(&bestRank[d], r); }
        }
        if (t == 0) scnt = 0;
        __syncthreads();
        // phase B
        for (u32 i = t; i < cnt; i += 1024) {
            u64 v = cur[i];
            u32 r = (u32)(v>>30), s = (u32)((v>>15)&0x7FFF), d = (u32)(v&0x7FFF);
            u32 as = atomicOr(&avail[s>>5], 0u), ad = atomicOr(&avail[d>>5], 0u);
            if (!(((as>>(s&31))&1u) && ((ad>>(d&31))&1u))) continue;
            u32 bs = atomicOr(&bestRank[s], 0u), bd = atomicOr(&bestRank[d], 0u);
            if (bs == r && bd == r) {
                matched[r] = 1;
                atomicAnd(&avail[s>>5], ~(1u<<(s&31)));
                atomicAnd(&avail[d>>5], ~(1u<<(d&31)));
            } else {
                u32 p = atomicAdd(&scnt, 1u);
                nxt[p] = v;
            }
        }
        __syncthreads();
        // phase C: reset bestRank of touched nodes
        for (u32 i = t; i < cnt; i += 1024) {
            u64 v = cur[i];
            u32 s = (u32)((v>>15)&0x7FFF), d = (u32)(v&0x7FFF);
            atomicExch(&bestRank[s], 0xFFFFFFFFu); atomicExch(&bestRank[d], 0xFFFFFFFFu);
        }
        __syncthreads();
        u32 ncnt = scnt;
        __syncthreads();
        cnt = ncnt;
        u64* tmp = cur; cur = nxt; nxt = tmp;
    }
}

// ---------------- cid assignment (stable prefix over rank order) ----------------
__global__ void ep_bsum(const unsigned char* matched, u32* bsums) {
    __shared__ u32 w[16];
    int t = threadIdx.x;
    int base = blockIdx.x*4096 + t*4;
    u32 s = (u32)matched[base] + matched[base+1] + matched[base+2] + matched[base+3];
    for (int off = 32; off; off >>= 1) s += __shfl_down(s, off, 64);
    if ((t&63) == 0) w[t>>6] = s;
    __syncthreads();
    if (t == 0) {
        u32 tot = 0;
        for (int i = 0; i < 16; i++) tot += w[i];
        bsums[blockIdx.x] = tot;
    }
}

__global__ void ep_bscan(u32* bsums, u32* counters) {
    int t = threadIdx.x; // 64 threads
    u32 v = bsums[t];
    u32 x = v;
    for (int off = 1; off < 64; off <<= 1) { u32 y = __shfl_up(x, off, 64); if (t >= off) x += y; }
    bsums[t] = x - v;
    if (t == 63) counters[2] = x; // n_merged
}

__global__ void ep_emit(const unsigned char* matched, const u32* bsums, const u32* pay,
                        const int* src, const int* dst, u64* Mlist, int* cl) {
    __shared__ u32 w[16];
    int t = threadIdx.x;
    int base = blockIdx.x*4096 + t*4;
    u32 f[4]; u32 s = 0;
    #pragma unroll
    for (int j = 0; j < 4; j++) { f[j] = matched[base+j]; s += f[j]; }
    u32 x = s;
    for (int off = 1; off < 64; off <<= 1) { u32 y = __shfl_up(x, off, 64); if ((t&63) >= off) x += y; }
    if ((t&63) == 63) w[t>>6] = x;
    __syncthreads();
    if (t < 16) {
        u32 ww = w[t];
        for (int off = 1; off < 16; off <<= 1) { u32 y = __shfl_up(ww, off, 16); if (t >= off) ww += y; }
        w[t] = ww;
    }
    __syncthreads();
    u32 excl = ((t>>6) ? w[(t>>6)-1] : 0u) + x - s;
    u32 pos = bsums[blockIdx.x] + excl;
    for (int j = 0; j < 4; j++) {
        if (f[j]) {
            int r = base + j;
            u32 o = pay[r];
            u32 ss = (u32)src[o], dd = (u32)dst[o];
            Mlist[pos] = ((u64)o << 30) | ((u64)ss << 15) | (u64)dd;
            cl[ss] = (int)pos; cl[dd] = (int)pos;
            pos++;
        }
    }
}

__global__ void ep_scanN(int* cl, u32* counters, float* out) {
    __shared__ u32 w[16];
    int t = threadIdx.x;
    int base = t*32;
    u32 s = 0;
    for (int j = 0; j < 32; j++) s += (cl[base+j] < 0) ? 1u : 0u;
    u32 x = s;
    for (int off = 1; off < 64; off <<= 1) { u32 y = __shfl_up(x, off, 64); if ((t&63) >= off) x += y; }
    if ((t&63) == 63) w[t>>6] = x;
    __syncthreads();
    if (t < 16) {
        u32 ww = w[t];
        for (int off = 1; off < 16; off <<= 1) { u32 y = __shfl_up(ww, off, 16); if (t >= off) ww += y; }
        w[t] = ww;
    }
    __syncthreads();
    u32 excl = ((t>>6) ? w[(t>>6)-1] : 0u) + x - s;
    u32 total = w[15];
    u32 nm = counters[2];
    if (t == 0) {
        counters[3] = nm + total;
        out[O4] = (float)(nm + total);
    }
    u32 run = nm + excl;
    for (int j = 0; j < 32; j++) { if (cl[base+j] < 0) cl[base+j] = (int)(run++); }
}

// ---------------- output init + scatters (f32 words) ----------------
__global__ void ep_init_out(float* out) {
    u32 i = blockIdx.x*blockDim.x + threadIdx.x;
    if (i < 4194304u) out[O0 + i] = 0.0f;              // new_x = 0
    if (i < 32768u) {
        out[O2 + i] = 0.0f;                            // new_batch = 0
        out[O3 + i] = 1.0f;                            // new_edge_score = 1.0
    }
}

__global__ void ep_out_nodes(const int* cl, const int* batch, const u32* counters, float* out) {
    int v = blockIdx.x*blockDim.x + threadIdx.x;
    if (v >= NN) return;
    int c = cl[v];
    out[O1 + v] = (float)c;
    if (c >= (int)counters[2]) out[O2 + c] = (float)batch[v]; // singleton
}

__global__ void ep_out_matched(const u64* Mlist, const int* batch, const u32* counters, float* out) {
    u32 i = blockIdx.x*blockDim.x + threadIdx.x;
    if (i >= counters[2]) return;
    u64 v = Mlist[i];
    u32 o = (u32)(v>>30), s = (u32)((v>>15)&0x7FFF), d = (u32)(v&0x7FFF);
    u32 mx = s > d ? s : d; // last-writer-wins (np sequential scatter) = max node index
    out[O2 + i] = (float)batch[mx];
    out[O3 + i] = out[O7 + o];
}

// ---------------- new_x rows: 32 rows/block, 8 rows/wave, k-outer ----------------
__global__ void ep_newx_m(const float* x, const float* Wt, const float* bt,
                          const u64* Mlist, const u32* counters, float* out) {
    __shared__ u64 ml[32];
    __shared__ float m[32][128];
    u32 nm = counters[2];
    u32 base = blockIdx.x * 32u;
    if (base >= nm) return;
    int t = threadIdx.x, lane = t & 63, wv = t >> 6;
    if (t < 32) { u32 r = base + (u32)t; ml[t] = (r < nm) ? Mlist[r] : 0ull; }
    __syncthreads();
    for (int i = t; i < 4096; i += 256) {
        int r = i >> 7, k = i & 127;
        u64 v = ml[r];
        u32 s = (u32)((v>>15)&0x7FFF), d = (u32)(v&0x7FFF);
        m[r][k] = x[s*NC+k] + x[d*NC+k];
    }
    __syncthreads();
    float a0[8], a1[8];
    #pragma unroll
    for (int r = 0; r < 8; r++) { a0[r] = bt[lane]; a1[r] = bt[lane+64]; }
    for (int k = 0; k < 128; k++) {
        float w0 = Wt[k*NC+lane], w1 = Wt[k*NC+lane+64];
        #pragma unroll
        for (int r = 0; r < 8; r++) { float mm = m[wv*8+r][k]; a0[r] += mm*w0; a1[r] += mm*w1; }
    }
    #pragma unroll
    for (int r = 0; r < 8; r++) {
        u32 row = base + (u32)(wv*8 + r);
        if (row < nm) {
            out[O0 + (size_t)row*NC + lane]      = a0[r];
            out[O0 + (size_t)row*NC + lane + 64] = a1[r];
        }
    }
}

__global__ void ep_newx_s(const float* x, const float* Wt, const float* bt,
                          const int* cl, const u32* counters, float* out) {
    __shared__ int rows[32];
    __shared__ float m[32][128];
    u32 nm = counters[2];
    u32 base = blockIdx.x * 32u; // node base; grid exactly covers NN
    int t = threadIdx.x, lane = t & 63, wv = t >> 6;
    if (t < 32) rows[t] = cl[base + t];
    __syncthreads();
    for (int i = t; i < 4096; i += 256) {
        int r = i >> 7, k = i & 127;
        m[r][k] = 2.0f * x[(base + r)*NC + k];
    }
    __syncthreads();
    float a0[8], a1[8];
    #pragma unroll
    for (int r = 0; r < 8; r++) { a0[r] = bt[lane]; a1[r] = bt[lane+64]; }
    for (int k = 0; k < 128; k++) {
        float w0 = Wt[k*NC+lane], w1 = Wt[k*NC+lane+64];
        #pragma unroll
        for (int r = 0; r < 8; r++) { float mm = m[wv*8+r][k]; a0[r] += mm*w0; a1[r] += mm*w1; }
    }
    #pragma unroll
    for (int r = 0; r < 8; r++) {
        int row = rows[wv*8 + r];
        if (row >= (int)nm) { // singleton node
            out[O0 + (size_t)row*NC + lane]      = a0[r];
            out[O0 + (size_t)row*NC + lane + 64] = a1[r];
        }
    }
}

// ---------------- new_ei + edge_valid via min-index hash ----------------
__global__ void ep_newei(const int* src, const int* dst, const int* cl,
                         u32* tkey, u32* tmin, float* out) {
    int e = blockIdx.x*blockDim.x + threadIdx.x;
    if (e >= NE) return;
    u32 cs = (u32)cl[src[e]], cd = (u32)cl[dst[e]];
    out[O5 + e]      = (float)cs;
    out[O5 + NE + e] = (float)cd;
    u32 key = (cs << 15) | cd;
    u32 slot = ((key * 2654435761u) >> 12) & (HCAP-1);
    while (true) {
        u32 k = tkey[slot];
        if (k == key) break;
        if (k == 0xFFFFFFFFu) {
            u32 old = atomicCAS(&tkey[slot], 0xFFFFFFFFu, key);
            if (old == 0xFFFFFFFFu || old == key) break;
            k = old;
        }
        slot = (slot + 1) & (HCAP-1);
    }
    atomicMin(&tmin[slot], (u32)e);
}

__global__ void ep_valid(const int* src, const int* dst, const int* cl,
                         const u32* tkey, const u32* tmin, float* out) {
    int e = blockIdx.x*blockDim.x + threadIdx.x;
    if (e >= NE) return;
    u32 cs = (u32)cl[src[e]], cd = (u32)cl[dst[e]];
    u32 key = (cs << 15) | cd;
    u32 slot = ((key * 2654435761u) >> 12) & (HCAP-1);
    while (tkey[slot] != key) slot = (slot + 1) & (HCAP-1);
    bool valid = (tmin[slot] == (u32)e) && (cs != cd);
    out[O6 + e] = valid ? 1.0f : 0.0f;
}

// =============================== host ===============================
extern "C" void kernel_launch(void* const* d_in, const int* in_sizes, int n_in,
                              void* d_out, int out_size, void* d_ws, size_t ws_size,
                              hipStream_t stream) {
    (void)in_sizes; (void)n_in; (void)out_size; (void)ws_size;
    const float* x    = (const float*)d_in[0];
    const int*   ei   = (const int*)d_in[1];
    const int*   src  = ei;
    const int*   dst  = ei + NE;
    const int*   batch= (const int*)d_in[2];
    const float* rnd  = (const float*)d_in[3];
    const float* Wt   = (const float*)d_in[4];
    const float* bt   = (const float*)d_in[5];
    const float* Ws   = (const float*)d_in[6];
    const float* bs   = (const float*)d_in[7];
    float* out = (float*)d_out;

    char* w = (char*)d_ws;
    double* u  = (double*)w;
    double* c0 = (double*)(w + 1024);
    u32* counters = (u32*)(w + 2048);
    size_t off = 4096;
    u64* keyA = (u64*)(w + off); off += (size_t)NE*8;
    u64* keyB = (u64*)(w + off); off += (size_t)NE*8;
    u32* payA = (u32*)(w + off); off += (size_t)NE*4;
    u32* payB = (u32*)(w + off); off += (size_t)NE*4;
    unsigned char* acc = (unsigned char*)(w + off); off += NE;
    u32* bestRank = (u32*)(w + off); off += (size_t)NN*4;
    u32* avail    = (u32*)(w + off); off += NN/8;
    unsigned char* matched = (unsigned char*)(w + off); off += NE;
    u64* frontA = (u64*)(w + off); off += (size_t)NE*8;
    u64* frontB = (u64*)(w + off); off += (size_t)NE*8;
    u64* Mlist  = (u64*)(w + off); off += (size_t)NN*8;
    int* cl     = (int*)(w + off); off += (size_t)NN*4;
    u32* bsums  = (u32*)(w + off); off += 256*4;
    u32* histG  = (u32*)(w + off); off += 256*256*4;
    u32* tkey   = (u32*)(w + off); off += (size_t)HCAP*4;
    u32* tmin   = (u32*)(w + off); off += (size_t)HCAP*4;

    ep_prep<<<1, 128, 0, stream>>>(Wt, Ws, bt, bs, u, c0, counters);
    ep_init<<<1024, 256, 0, stream>>>(bestRank, avail, matched, cl);
    hipMemsetAsync(tkey, 0xFF, (size_t)HCAP*4, stream);
    hipMemsetAsync(tmin, 0xFF, (size_t)HCAP*4, stream);

    ep_scores<<<65536, 256, 0, stream>>>(x, src, dst, rnd, u, c0, keyA, payA, acc, out);

    u64 *ki = keyA, *ko = keyB; u32 *pi = payA, *po = payB;
    for (int p = 0; p < 8; p++) {
        ep_hist<<<SB, 64, 0, stream>>>(ki, histG, p*8);
        ep_hscan<<<1, 1024, 0, stream>>>(histG);
        ep_scatter<<<SB, 64, 0, stream>>>(ki, pi, ko, po, histG, p*8);
        u64* tk = ki; ki = ko; ko = tk;
        u32* tp = pi; pi = po; po = tp;
    }
    // after 8 passes sorted data is back in keyA/payA

    ep_build<<<1024, 256, 0, stream>>>(payA, acc, src, dst, frontA, counters);
    ep_roundA<<<1024, 256, 0, stream>>>(frontA, counters, bestRank, avail);
    ep_roundB<<<1024, 256, 0, stream>>>(frontA, counters, bestRank, avail, matched, frontB);
    ep_roundC<<<128, 256, 0, stream>>>(bestRank);
    ep_finish<<<1, 1024, 0, stream>>>(frontB, frontA, counters, bestRank, avail, matched);

    ep_bsum<<<64, 1024, 0, stream>>>(matched, bsums);
    ep_bscan<<<1, 64, 0, stream>>>(bsums, counters);
    ep_emit<<<64, 1024, 0, stream>>>(matched, bsums, payA, src, dst, Mlist, cl);
    ep_scanN<<<1, 1024, 0, stream>>>(cl, counters, out);

    ep_init_out<<<16384, 256, 0, stream>>>(out);
    ep_out_nodes<<<128, 256, 0, stream>>>(cl, batch, counters, out);
    ep_out_matched<<<128, 256, 0, stream>>>(Mlist, batch, counters, out);

    ep_newx_m<<<1024, 256, 0, stream>>>(x, Wt, bt, Mlist, counters, out);
    ep_newx_s<<<1024, 256, 0, stream>>>(x, Wt, bt, cl, counters, out);

    ep_newei<<<1024, 256, 0, stream>>>(src, dst, cl, tkey, tmin, out);
    ep_valid<<<1024, 256, 0, stream>>>(src, dst, cl, tkey, tmin, out);
}

// Round 3
// 875.550 us; speedup vs baseline: 7.0977x; 7.0977x over previous
//
#include <hip/hip_runtime.h>
#include <stdint.h>

typedef unsigned int u32;
typedef unsigned long long u64;

#define NN 32768
#define NE 262144
#define NC 128

// output element offsets (ALL FLOAT32)
#define O0 0u               // new_x [NN*128]
#define O1 4194304u         // cluster [NN]
#define O2 4227072u         // new_batch [NN]
#define O3 4259840u         // new_edge_score [NN]
#define O4 4292608u         // num_clusters [1]
#define O5 4292609u         // new_ei [2*NE]
#define O6 4816897u         // edge_valid [NE]
#define O7 5079041u         // e [NE]

#define HCAP (1u<<20)
#define SB 256   // sort blocks
#define SC 1024  // items per sort block
#define CNT0 8   // first frontier-counter slot
#define NFULL 12 // full-grid matching rounds before tail

// ---------------- prep: u = W_t @ W_s (f64), c0 = b_t@W_s + b_s; zero counters ----
__global__ void ep_prep(const float* Wt, const float* Ws, const float* bt, const float* bs,
                        double* u, double* c0, u32* counters) {
    int i = threadIdx.x;
    double s = 0.0;
    for (int j = 0; j < NC; j++) s += (double)Wt[i*NC+j] * (double)Ws[j];
    u[i] = s;
    if (i == 0) {
        double c = 0.0;
        for (int j = 0; j < NC; j++) c += (double)bt[j] * (double)Ws[j];
        *c0 = c + (double)bs[0];
    }
    if (i < 64) counters[i] = 0u;
}

// ---------------- per-call state init ----------------
__global__ void ep_init(u64* bestT, u32* avail, unsigned char* matched, int* cl) {
    int i = blockIdx.x*blockDim.x + threadIdx.x;
    if (i < NE) matched[i] = 0;
    if (i < NN) { bestT[i] = 0xFFFFFFFFFFFFFFFFull; cl[i] = -1; }
    if (i < NN/32) avail[i] = 0xFFFFFFFFu;
}

// ---------------- scores: one wave per edge, f64 dot ----------------
__global__ void ep_scores(const float* x, const int* src, const int* dst, const float* rnd,
                          const double* u, const double* c0,
                          u64* keyA, u32* payA, unsigned char* acc, float* out) {
    int gid = blockIdx.x*blockDim.x + threadIdx.x;
    int wid = gid >> 6;
    int lane = threadIdx.x & 63;
    if (wid >= NE) return;
    int s = src[wid], d = dst[wid];
    double m0 = (double)x[s*NC+lane]    + (double)x[d*NC+lane];
    double m1 = (double)x[s*NC+lane+64] + (double)x[d*NC+lane+64];
    double t = m0*u[lane] + m1*u[lane+64];
    for (int off = 32; off; off >>= 1) t += __shfl_down(t, off, 64);
    if (lane == 0) {
        double z = t + *c0;
        double sc = 1.0/(1.0 + exp(-z));
        u64 b = (u64)__double_as_longlong(z);
        u64 ord = (b & 0x8000000000000000ull) ? ~b : (b | 0x8000000000000000ull); // ascending z
        keyA[wid] = ~ord;   // ascending key == descending z
        payA[wid] = (u32)wid;
        acc[wid] = ((double)rnd[wid] <= sc) ? 1 : 0;
        out[O7 + wid] = (float)sc;
    }
}

// ---------------- radix sort (LSD, 8x8-bit, stable) ----------------
__global__ void ep_hist(const u64* key, u32* histG, int shift) {
    __shared__ u32 h[256];
    int t = threadIdx.x; // 64 threads
    for (int i = t; i < 256; i += 64) h[i] = 0;
    __syncthreads();
    int base = blockIdx.x*SC + t*16;
    for (int j = 0; j < 16; j++) {
        u32 dgt = (u32)(key[base+j] >> shift) & 255u;
        atomicAdd(&h[dgt], 1u);
    }
    __syncthreads();
    for (int i = t; i < 256; i += 64) histG[i*SB + blockIdx.x] = h[i];
}

__global__ void ep_hscan(u32* histG) { // exclusive scan of 65536 u32, 1024 threads
    __shared__ u32 w[16];
    int t = threadIdx.x;
    int base = t*64;
    u32 s = 0;
    for (int j = 0; j < 64; j++) s += histG[base+j];
    u32 x = s;
    for (int off = 1; off < 64; off <<= 1) { u32 y = __shfl_up(x, off, 64); if ((t&63) >= off) x += y; }
    if ((t&63) == 63) w[t>>6] = x;
    __syncthreads();
    if (t < 16) {
        u32 ww = w[t];
        for (int off = 1; off < 16; off <<= 1) { u32 y = __shfl_up(ww, off, 16); if (t >= off) ww += y; }
        w[t] = ww;
    }
    __syncthreads();
    u32 excl = ((t>>6) ? w[(t>>6)-1] : 0u) + x - s;
    u32 run = excl;
    for (int j = 0; j < 64; j++) { u32 tmp = histG[base+j]; histG[base+j] = run; run += tmp; }
}

__global__ void ep_scatter(const u64* keyIn, const u32* payIn, u64* keyOut, u32* payOut,
                           const u32* histG, int shift) {
    __shared__ unsigned short m[256][64]; // 32 KiB
    int t = threadIdx.x; // 64 threads
    for (int i = t; i < 256*64/2; i += 64) ((u32*)m)[i] = 0u;
    __syncthreads();
    int base = blockIdx.x*SC + t*16;
    u64 kreg[16]; u32 dg[16];
    #pragma unroll
    for (int j = 0; j < 16; j++) {
        kreg[j] = keyIn[base+j];
        dg[j] = (u32)(kreg[j] >> shift) & 255u;
        m[dg[j]][t]++;
    }
    __syncthreads();
    for (int k = 0; k < 4; k++) {
        int d = t*4 + k;
        u32 run = 0;
        for (int tt = 0; tt < 64; tt++) { u32 tmp = m[d][tt]; m[d][tt] = (unsigned short)run; run += tmp; }
    }
    __syncthreads();
    #pragma unroll
    for (int j = 0; j < 16; j++) {
        u32 d = dg[j];
        u32 pos = histG[d*SB + blockIdx.x] + m[d][t];
        m[d][t]++;
        keyOut[pos] = kreg[j];
        payOut[pos] = payIn[base+j];
    }
}

// ---------------- matching: tagged-bestRank priority matching ----------------
__device__ __forceinline__ bool ep_bit(const u32* a, u32 v) { return (a[v>>5] >> (v&31)) & 1u; }
__device__ __forceinline__ u64 ep_tag(u32 round, u32 r) {
    return ((u64)(0xFFFFFFFEu - round) << 32) | (u64)r;
}

__global__ void ep_build(const u32* pay, const unsigned char* acc, const int* src, const int* dst,
                         u64* front, u32* counters) {
    int r = blockIdx.x*blockDim.x + threadIdx.x;
    if (r >= NE) return;
    u32 o = pay[r];
    if (!acc[o]) return;
    u32 s = (u32)src[o], d = (u32)dst[o];
    u32 p = atomicAdd(&counters[CNT0], 1u);
    front[p] = ((u64)(u32)r << 30) | ((u64)s << 15) | (u64)d;
}

__global__ void ep_mroundA(const u64* front, const u32* cnt, u64* bestT, const u32* avail, u32 round) {
    u32 n = *cnt;
    u32 i = blockIdx.x*blockDim.x + threadIdx.x;
    if (i >= n) return;
    u64 v = front[i];
    u32 r = (u32)(v>>30), s = (u32)((v>>15)&0x7FFF), d = (u32)(v&0x7FFF);
    if (ep_bit(avail, s) && ep_bit(avail, d)) {
        u64 tag = ep_tag(round, r);
        atomicMin(&bestT[s], tag); atomicMin(&bestT[d], tag);
    }
}

__global__ void ep_mroundB(const u64* front, const u32* cnt, u32* cntNxt, u64* nxt,
                           const u64* bestT, u32* avail, unsigned char* matched, u32 round) {
    u32 n = *cnt;
    u32 i = blockIdx.x*blockDim.x + threadIdx.x;
    if (i >= n) return;
    u64 v = front[i];
    u32 r = (u32)(v>>30), s = (u32)((v>>15)&0x7FFF), d = (u32)(v&0x7FFF);
    if (!ep_bit(avail, s) || !ep_bit(avail, d)) return; // dead
    u64 tag = ep_tag(round, r);
    if (bestT[s] == tag && bestT[d] == tag) {
        matched[r] = 1;
        atomicAnd(&avail[s>>5], ~(1u<<(s&31)));
        atomicAnd(&avail[d>>5], ~(1u<<(d&31)));
    } else {
        u32 p = atomicAdd(cntNxt, 1u);
        nxt[p] = v;
    }
}

__global__ void __launch_bounds__(1024) ep_mtail(u64* fa, u64* fb, const u32* cntIn,
                                                 u64* bestT, u32* avail, unsigned char* matched,
                                                 u32 baseRound) {
    __shared__ u32 scnt;
    int t = threadIdx.x;
    u64* cur = fa; u64* nxt = fb;
    u32 cnt = *cntIn;
    for (u32 round = baseRound; cnt != 0 && round < baseRound + 200000u; round++) {
        // phase A (atomic reads: fresh L2 values)
        for (u32 i = t; i < cnt; i += 1024) {
            u64 v = cur[i];
            u32 r = (u32)(v>>30), s = (u32)((v>>15)&0x7FFF), d = (u32)(v&0x7FFF);
            u32 as = atomicOr(&avail[s>>5], 0u), ad = atomicOr(&avail[d>>5], 0u);
            if (((as>>(s&31))&1u) && ((ad>>(d&31))&1u)) {
                u64 tag = ep_tag(round, r);
                atomicMin(&bestT[s], tag); atomicMin(&bestT[d], tag);
            }
        }
        if (t == 0) scnt = 0;
        __syncthreads();
        // phase B
        for (u32 i = t; i < cnt; i += 1024) {
            u64 v = cur[i];
            u32 r = (u32)(v>>30), s = (u32)((v>>15)&0x7FFF), d = (u32)(v&0x7FFF);
            u32 as = atomicOr(&avail[s>>5], 0u), ad = atomicOr(&avail[d>>5], 0u);
            if (!(((as>>(s&31))&1u) && ((ad>>(d&31))&1u))) continue;
            u64 tag = ep_tag(round, r);
            u64 bs = atomicOr(&bestT[s], 0ull), bd = atomicOr(&bestT[d], 0ull);
            if (bs == tag && bd == tag) {
                matched[r] = 1;
                atomicAnd(&avail[s>>5], ~(1u<<(s&31)));
                atomicAnd(&avail[d>>5], ~(1u<<(d&31)));
            } else {
                u32 p = atomicAdd(&scnt, 1u);
                nxt[p] = v;
            }
        }
        __syncthreads();
        u32 ncnt = scnt;
        __syncthreads();
        cnt = ncnt;
        u64* tmp = cur; cur = nxt; nxt = tmp;
    }
}

// ---------------- cid assignment (stable prefix over rank order) ----------------
__global__ void ep_bsum(const unsigned char* matched, u32* bsums) {
    __shared__ u32 w[16];
    int t = threadIdx.x;
    int base = blockIdx.x*4096 + t*4;
    u32 s = (u32)matched[base] + matched[base+1] + matched[base+2] + matched[base+3];
    for (int off = 32; off; off >>= 1) s += __shfl_down(s, off, 64);
    if ((t&63) == 0) w[t>>6] = s;
    __syncthreads();
    if (t == 0) {
        u32 tot = 0;
        for (int i = 0; i < 16; i++) tot += w[i];
        bsums[blockIdx.x] = tot;
    }
}

__global__ void ep_bscan(u32* bsums, u32* counters) {
    int t = threadIdx.x; // 64 threads
    u32 v = bsums[t];
    u32 x = v;
    for (int off = 1; off < 64; off <<= 1) { u32 y = __shfl_up(x, off, 64); if (t >= off) x += y; }
    bsums[t] = x - v;
    if (t == 63) counters[2] = x; // n_merged
}

__global__ void ep_emit(const unsigned char* matched, const u32* bsums, const u32* pay,
                        const int* src, const int* dst, u64* Mlist, int* cl) {
    __shared__ u32 w[16];
    int t = threadIdx.x;
    int base = blockIdx.x*4096 + t*4;
    u32 f[4]; u32 s = 0;
    #pragma unroll
    for (int j = 0; j < 4; j++) { f[j] = matched[base+j]; s += f[j]; }
    u32 x = s;
    for (int off = 1; off < 64; off <<= 1) { u32 y = __shfl_up(x, off, 64); if ((t&63) >= off) x += y; }
    if ((t&63) == 63) w[t>>6] = x;
    __syncthreads();
    if (t < 16) {
        u32 ww = w[t];
        for (int off = 1; off < 16; off <<= 1) { u32 y = __shfl_up(ww, off, 16); if (t >= off) ww += y; }
        w[t] = ww;
    }
    __syncthreads();
    u32 excl = ((t>>6) ? w[(t>>6)-1] : 0u) + x - s;
    u32 pos = bsums[blockIdx.x] + excl;
    for (int j = 0; j < 4; j++) {
        if (f[j]) {
            int r = base + j;
            u32 o = pay[r];
            u32 ss = (u32)src[o], dd = (u32)dst[o];
            Mlist[pos] = ((u64)o << 30) | ((u64)ss << 15) | (u64)dd;
            cl[ss] = (int)pos; cl[dd] = (int)pos;
            pos++;
        }
    }
}

__global__ void ep_scanN(int* cl, u32* counters, float* out) {
    __shared__ u32 w[16];
    int t = threadIdx.x;
    int base = t*32;
    u32 s = 0;
    for (int j = 0; j < 32; j++) s += (cl[base+j] < 0) ? 1u : 0u;
    u32 x = s;
    for (int off = 1; off < 64; off <<= 1) { u32 y = __shfl_up(x, off, 64); if ((t&63) >= off) x += y; }
    if ((t&63) == 63) w[t>>6] = x;
    __syncthreads();
    if (t < 16) {
        u32 ww = w[t];
        for (int off = 1; off < 16; off <<= 1) { u32 y = __shfl_up(ww, off, 16); if (t >= off) ww += y; }
        w[t] = ww;
    }
    __syncthreads();
    u32 excl = ((t>>6) ? w[(t>>6)-1] : 0u) + x - s;
    u32 total = w[15];
    u32 nm = counters[2];
    if (t == 0) {
        counters[3] = nm + total;
        out[O4] = (float)(nm + total);
    }
    u32 run = nm + excl;
    for (int j = 0; j < 32; j++) { if (cl[base+j] < 0) cl[base+j] = (int)(run++); }
}

// ---------------- output init + scatters (f32 words) ----------------
__global__ void ep_init_out(float* out) {
    u32 i = blockIdx.x*blockDim.x + threadIdx.x;
    if (i < 4194304u) out[O0 + i] = 0.0f;              // new_x = 0
    if (i < 32768u) {
        out[O2 + i] = 0.0f;                            // new_batch = 0
        out[O3 + i] = 1.0f;                            // new_edge_score = 1.0
    }
}

__global__ void ep_out_nodes(const int* cl, const int* batch, const u32* counters, float* out) {
    int v = blockIdx.x*blockDim.x + threadIdx.x;
    if (v >= NN) return;
    int c = cl[v];
    out[O1 + v] = (float)c;
    if (c >= (int)counters[2]) out[O2 + c] = (float)batch[v]; // singleton
}

__global__ void ep_out_matched(const u64* Mlist, const int* batch, const u32* counters, float* out) {
    u32 i = blockIdx.x*blockDim.x + threadIdx.x;
    if (i >= counters[2]) return;
    u64 v = Mlist[i];
    u32 o = (u32)(v>>30), s = (u32)((v>>15)&0x7FFF), d = (u32)(v&0x7FFF);
    u32 mx = s > d ? s : d; // last-writer-wins (sequential scatter) = max node index
    out[O2 + i] = (float)batch[mx];
    out[O3 + i] = out[O7 + o];
}

// ---------------- new_x rows: 32 rows/block, 8 rows/wave, k-outer ----------------
__global__ void ep_newx_m(const float* x, const float* Wt, const float* bt,
                          const u64* Mlist, const u32* counters, float* out) {
    __shared__ u64 ml[32];
    __shared__ float m[32][128];
    u32 nm = counters[2];
    u32 base = blockIdx.x * 32u;
    if (base >= nm) return;
    int t = threadIdx.x, lane = t & 63, wv = t >> 6;
    if (t < 32) { u32 r = base + (u32)t; ml[t] = (r < nm) ? Mlist[r] : 0ull; }
    __syncthreads();
    for (int i = t; i < 4096; i += 256) {
        int r = i >> 7, k = i & 127;
        u64 v = ml[r];
        u32 s = (u32)((v>>15)&0x7FFF), d = (u32)(v&0x7FFF);
        m[r][k] = x[s*NC+k] + x[d*NC+k];
    }
    __syncthreads();
    float a0[8], a1[8];
    #pragma unroll
    for (int r = 0; r < 8; r++) { a0[r] = bt[lane]; a1[r] = bt[lane+64]; }
    for (int k = 0; k < 128; k++) {
        float w0 = Wt[k*NC+lane], w1 = Wt[k*NC+lane+64];
        #pragma unroll
        for (int r = 0; r < 8; r++) { float mm = m[wv*8+r][k]; a0[r] += mm*w0; a1[r] += mm*w1; }
    }
    #pragma unroll
    for (int r = 0; r < 8; r++) {
        u32 row = base + (u32)(wv*8 + r);
        if (row < nm) {
            out[O0 + (size_t)row*NC + lane]      = a0[r];
            out[O0 + (size_t)row*NC + lane + 64] = a1[r];
        }
    }
}

__global__ void ep_newx_s(const float* x, const float* Wt, const float* bt,
                          const int* cl, const u32* counters, float* out) {
    __shared__ int rows[32];
    __shared__ float m[32][128];
    u32 nm = counters[2];
    u32 base = blockIdx.x * 32u;
    int t = threadIdx.x, lane = t & 63, wv = t >> 6;
    if (t < 32) rows[t] = cl[base + t];
    __syncthreads();
    for (int i = t; i < 4096; i += 256) {
        int r = i >> 7, k = i & 127;
        m[r][k] = 2.0f * x[(base + r)*NC + k];
    }
    __syncthreads();
    float a0[8], a1[8];
    #pragma unroll
    for (int r = 0; r < 8; r++) { a0[r] = bt[lane]; a1[r] = bt[lane+64]; }
    for (int k = 0; k < 128; k++) {
        float w0 = Wt[k*NC+lane], w1 = Wt[k*NC+lane+64];
        #pragma unroll
        for (int r = 0; r < 8; r++) { float mm = m[wv*8+r][k]; a0[r] += mm*w0; a1[r] += mm*w1; }
    }
    #pragma unroll
    for (int r = 0; r < 8; r++) {
        int row = rows[wv*8 + r];
        if (row >= (int)nm) { // singleton node
            out[O0 + (size_t)row*NC + lane]      = a0[r];
            out[O0 + (size_t)row*NC + lane + 64] = a1[r];
        }
    }
}

// ---------------- new_ei + edge_valid via min-index hash ----------------
__global__ void ep_newei(const int* src, const int* dst, const int* cl,
                         u32* tkey, u32* tmin, float* out) {
    int e = blockIdx.x*blockDim.x + threadIdx.x;
    if (e >= NE) return;
    u32 cs = (u32)cl[src[e]], cd = (u32)cl[dst[e]];
    out[O5 + e]      = (float)cs;
    out[O5 + NE + e] = (float)cd;
    u32 key = (cs << 15) | cd;
    u32 slot = ((key * 2654435761u) >> 12) & (HCAP-1);
    while (true) {
        u32 k = tkey[slot];
        if (k == key) break;
        if (k == 0xFFFFFFFFu) {
            u32 old = atomicCAS(&tkey[slot], 0xFFFFFFFFu, key);
            if (old == 0xFFFFFFFFu || old == key) break;
            k = old;
        }
        slot = (slot + 1) & (HCAP-1);
    }
    atomicMin(&tmin[slot], (u32)e);
}

__global__ void ep_valid(const int* src, const int* dst, const int* cl,
                         const u32* tkey, const u32* tmin, float* out) {
    int e = blockIdx.x*blockDim.x + threadIdx.x;
    if (e >= NE) return;
    u32 cs = (u32)cl[src[e]], cd = (u32)cl[dst[e]];
    u32 key = (cs << 15) | cd;
    u32 slot = ((key * 2654435761u) >> 12) & (HCAP-1);
    while (tkey[slot] != key) slot = (slot + 1) & (HCAP-1);
    bool valid = (tmin[slot] == (u32)e) && (cs != cd);
    out[O6 + e] = valid ? 1.0f : 0.0f;
}

// =============================== host ===============================
extern "C" void kernel_launch(void* const* d_in, const int* in_sizes, int n_in,
                              void* d_out, int out_size, void* d_ws, size_t ws_size,
                              hipStream_t stream) {
    (void)in_sizes; (void)n_in; (void)out_size; (void)ws_size;
    const float* x    = (const float*)d_in[0];
    const int*   ei   = (const int*)d_in[1];
    const int*   src  = ei;
    const int*   dst  = ei + NE;
    const int*   batch= (const int*)d_in[2];
    const float* rnd  = (const float*)d_in[3];
    const float* Wt   = (const float*)d_in[4];
    const float* bt   = (const float*)d_in[5];
    const float* Ws   = (const float*)d_in[6];
    const float* bs   = (const float*)d_in[7];
    float* out = (float*)d_out;

    char* w = (char*)d_ws;
    double* u  = (double*)w;
    double* c0 = (double*)(w + 1024);
    u32* counters = (u32*)(w + 2048);
    size_t off = 4096;
    u64* keyA = (u64*)(w + off); off += (size_t)NE*8;
    u64* keyB = (u64*)(w + off); off += (size_t)NE*8;
    u32* payA = (u32*)(w + off); off += (size_t)NE*4;
    u32* payB = (u32*)(w + off); off += (size_t)NE*4;
    unsigned char* acc = (unsigned char*)(w + off); off += NE;
    u64* bestT    = (u64*)(w + off); off += (size_t)NN*8;
    u32* avail    = (u32*)(w + off); off += NN/8;
    unsigned char* matched = (unsigned char*)(w + off); off += NE;
    u64* frontA = (u64*)(w + off); off += (size_t)NE*8;
    u64* frontB = (u64*)(w + off); off += (size_t)NE*8;
    u64* Mlist  = (u64*)(w + off); off += (size_t)NN*8;
    int* cl     = (int*)(w + off); off += (size_t)NN*4;
    u32* bsums  = (u32*)(w + off); off += 256*4;
    u32* histG  = (u32*)(w + off); off += 256*256*4;
    u32* tkey   = (u32*)(w + off); off += (size_t)HCAP*4;
    u32* tmin   = (u32*)(w + off); off += (size_t)HCAP*4;

    ep_prep<<<1, 128, 0, stream>>>(Wt, Ws, bt, bs, u, c0, counters);
    ep_init<<<1024, 256, 0, stream>>>(bestT, avail, matched, cl);
    hipMemsetAsync(tkey, 0xFF, (size_t)HCAP*4, stream);
    hipMemsetAsync(tmin, 0xFF, (size_t)HCAP*4, stream);

    ep_scores<<<65536, 256, 0, stream>>>(x, src, dst, rnd, u, c0, keyA, payA, acc, out);

    u64 *ki = keyA, *ko = keyB; u32 *pi = payA, *po = payB;
    for (int p = 0; p < 8; p++) {
        ep_hist<<<SB, 64, 0, stream>>>(ki, histG, p*8);
        ep_hscan<<<1, 1024, 0, stream>>>(histG);
        ep_scatter<<<SB, 64, 0, stream>>>(ki, pi, ko, po, histG, p*8);
        u64* tk = ki; ki = ko; ko = tk;
        u32* tp = pi; pi = po; po = tp;
    }
    // after 8 passes sorted data is back in keyA/payA

    ep_build<<<1024, 256, 0, stream>>>(payA, acc, src, dst, frontA, counters);

    // NFULL full-grid tagged priority-matching rounds, then single-block tail
    u64 *fc = frontA, *fn = frontB;
    for (u32 rd = 0; rd < NFULL; rd++) {
        ep_mroundA<<<1024, 256, 0, stream>>>(fc, &counters[CNT0+rd], bestT, avail, rd);
        ep_mroundB<<<1024, 256, 0, stream>>>(fc, &counters[CNT0+rd], &counters[CNT0+rd+1], fn,
                                             bestT, avail, matched, rd);
        u64* tf = fc; fc = fn; fn = tf;
    }
    ep_mtail<<<1, 1024, 0, stream>>>(fc, fn, &counters[CNT0+NFULL], bestT, avail, matched, NFULL);

    ep_bsum<<<64, 1024, 0, stream>>>(matched, bsums);
    ep_bscan<<<1, 64, 0, stream>>>(bsums, counters);
    ep_emit<<<64, 1024, 0, stream>>>(matched, bsums, payA, src, dst, Mlist, cl);
    ep_scanN<<<1, 1024, 0, stream>>>(cl, counters, out);

    ep_init_out<<<16384, 256, 0, stream>>>(out);
    ep_out_nodes<<<128, 256, 0, stream>>>(cl, batch, counters, out);
    ep_out_matched<<<128, 256, 0, stream>>>(Mlist, batch, counters, out);

    ep_newx_m<<<1024, 256, 0, stream>>>(x, Wt, bt, Mlist, counters, out);
    ep_newx_s<<<1024, 256, 0, stream>>>(x, Wt, bt, cl, counters, out);

    ep_newei<<<1024, 256, 0, stream>>>(src, dst, cl, tkey, tmin, out);
    ep_valid<<<1024, 256, 0, stream>>>(src, dst, cl, tkey, tmin, out);
}